// Round 23
// baseline (186.188 us; speedup 1.0000x reference)
//
#include <hip/hip_runtime.h>
#include <cmath>

#define NB    16
#define TT1   2048
#define TT2   512
#define NATT  256
#define TEMP  0.0005f

// workspace element counts (ushort = bf16 unless noted)
#define KP_SZ   (NB*514*256)
#define KE_SZ   (NB*512*256)
#define QP_SZ   (NB*2050*80)
#define QE_SZ   (NB*2048*256)
#define W1T_SZ  (512*768)
#define W2T_SZ  (256*512)
#define W3T_SZ  (160*256)
#define W4T_SZ  (80*160)
#define W5T_SZ  (256*96)
#define WTOT_SZ (W1T_SZ+W2T_SZ+W3T_SZ+W4T_SZ+W5T_SZ)
#define LGP_SZ  (NB*TT1*TT2)

// prep grid (plt first: heaviest stream starts earliest)
#define PREP_PLT_BLK  ((TT1/64)*(TT2/64)*NB)   // 4096
#define PREP_PK_BLK   (KP_SZ/256)              // 8224
#define PREP_WT_BLK   (WTOT_SZ/256)            // 2354
#define PREP_QT_BLK   (NB*(TT1/64))            // 512
// conv grid
#define CONV_KEY_BLK  (NB*512/32)              // 256
#define CONV_QRY_BLK  (NB*2048/128)            // 256

typedef __attribute__((ext_vector_type(8))) short short8v;
typedef __attribute__((ext_vector_type(4))) float f32x4;

__device__ inline ushort f2bf(float f) {
    unsigned int u = __float_as_uint(f);
    u += 0x7fff + ((u >> 16) & 1);      // RNE
    return (ushort)(u >> 16);
}
__device__ inline float bf2f(ushort u) {
    return __uint_as_float(((unsigned int)u) << 16);
}

// ==================== KERNEL 1: prep (plt | pad_keys | wtrans | query transpose) ====================

__global__ __launch_bounds__(256) void prep_kernel(
    const float* __restrict__ keys, ushort* __restrict__ kp,
    const float* __restrict__ kw1, const float* __restrict__ kw2,
    const float* __restrict__ qw1, const float* __restrict__ qw2,
    const float* __restrict__ qw3,
    ushort* __restrict__ w1t, ushort* __restrict__ w2t, ushort* __restrict__ w3t,
    ushort* __restrict__ w4t, ushort* __restrict__ w5t,
    const float* __restrict__ queries, ushort* __restrict__ qp,
    const float* __restrict__ prior, ushort* __restrict__ lgp)
{
    __shared__ float T[80][65];
    const int bx  = blockIdx.x;
    const int tid = threadIdx.x;

    if (bx < PREP_PLT_BLK) {
        // ---- prior: transpose + log -> bf16 (64x64 tile), f32x4 nt reads ----
        const int l    = bx;
        const int t1_0 = (l & 31) * 64;
        const int t2_0 = ((l >> 5) & 7) * 64;
        const int b    = l >> 8;
        const int j4 = tid & 15;           // 16 f32x4 per row
        const int r0 = tid >> 4;           // 16 rows per pass
        #pragma unroll
        for (int p = 0; p < 4; ++p) {
            const f32x4 v = __builtin_nontemporal_load(
                (const f32x4*)(prior + ((size_t)b * TT2 + t2_0 + r0 + p * 16) * TT1
                                + t1_0 + j4 * 4));
            T[r0 + p * 16][j4 * 4 + 0] = v.x;
            T[r0 + p * 16][j4 * 4 + 1] = v.y;
            T[r0 + p * 16][j4 * 4 + 2] = v.z;
            T[r0 + p * 16][j4 * 4 + 3] = v.w;
        }
        __syncthreads();
        const int j  = tid & 63;
        const int i0 = (tid >> 6) * 16;
        #pragma unroll
        for (int r = 0; r < 16; ++r) {
            const int p = i0 + r;
            const float v = T[j][p];
            lgp[((size_t)b * TT1 + t1_0 + p) * TT2 + t2_0 + j] = f2bf(__logf(v + 1e-8f));
        }
        return;
    }
    if (bx < PREP_PLT_BLK + PREP_PK_BLK) {
        const int idx = (bx - PREP_PLT_BLK) * 256 + tid;
        int c = idx & 255;
        int r = (idx >> 8) % 514;
        int b = idx / (514 * 256);
        float v = 0.f;
        if (r >= 1 && r <= 512)
            v = keys[((size_t)b * 512 + (r - 1)) * 256 + c];
        kp[idx] = f2bf(v);
        return;
    }
    if (bx < PREP_PLT_BLK + PREP_PK_BLK + PREP_WT_BLK) {
        int idx = (bx - PREP_PLT_BLK - PREP_PK_BLK) * 256 + tid;
        const float* w; ushort* wt; int Kreal, Kpad, N;
        if (idx < W1T_SZ) {
            w = kw1; wt = w1t; Kreal = 768; Kpad = 768; N = 512;
        } else if ((idx -= W1T_SZ) < W2T_SZ) {
            w = kw2; wt = w2t; Kreal = 512; Kpad = 512; N = 256;
        } else if ((idx -= W2T_SZ) < W3T_SZ) {
            w = qw1; wt = w3t; Kreal = 240; Kpad = 256; N = 160;
        } else if ((idx -= W3T_SZ) < W4T_SZ) {
            w = qw2; wt = w4t; Kreal = 160; Kpad = 160; N = 80;
        } else {
            idx -= W4T_SZ;
            w = qw3; wt = w5t; Kreal = 80; Kpad = 96; N = 256;
        }
        int k = idx % Kpad;
        int n = idx / Kpad;
        wt[idx] = (k < Kreal) ? f2bf(w[(size_t)k * N + n]) : (ushort)0;
        return;
    }
    // ---- query transpose (LDS-tiled) ----
    {
        const int l  = bx - PREP_PLT_BLK - PREP_PK_BLK - PREP_WT_BLK;   // [0, 512)
        const int b  = l >> 5;
        const int t0 = (l & 31) * 64;
        const int g  = tid >> 6;
        const int j  = tid & 63;
        #pragma unroll
        for (int r = 0; r < 20; ++r) {
            const int c = g * 20 + r;
            T[c][j] = queries[((size_t)b * 80 + c) * 2048 + t0 + j];
        }
        __syncthreads();
        const int tt = tid >> 2;
        const int c0 = (tid & 3) * 20;
        ushort* qrow = qp + (size_t)b * (2050 * 80) + (size_t)(t0 + tt + 1) * 80 + c0;
        #pragma unroll
        for (int i4 = 0; i4 < 5; ++i4) {
            ushort4 st;
            st.x = f2bf(T[c0 + i4 * 4 + 0][tt]);
            st.y = f2bf(T[c0 + i4 * 4 + 1][tt]);
            st.z = f2bf(T[c0 + i4 * 4 + 2][tt]);
            st.w = f2bf(T[c0 + i4 * 4 + 3][tt]);
            *(ushort4*)(qrow + i4 * 4) = st;
        }
        if (t0 == 0 && tid < 80)
            qp[(size_t)b * (2050 * 80) + tid] = 0;
        if (t0 == 2048 - 64 && tid < 80)
            qp[(size_t)b * (2050 * 80) + (size_t)2049 * 80 + tid] = 0;
    }
}

// ==================== KERNEL 2: conv (key | query), rf=2 + software-pipelined loads ====================

__global__ __launch_bounds__(512, 4) void conv_kernel(
    const ushort* __restrict__ kp, const ushort* __restrict__ w1t,
    const float* __restrict__ kb1, const ushort* __restrict__ w2t,
    const float* __restrict__ kb2, ushort* __restrict__ ke, float* __restrict__ k2,
    const ushort* __restrict__ qp, const ushort* __restrict__ w3t,
    const float* __restrict__ qb1, const ushort* __restrict__ w4t,
    const float* __restrict__ qb2, const ushort* __restrict__ w5t,
    const float* __restrict__ qb3, ushort* __restrict__ qe)
{
    __shared__ __align__(16) unsigned char smem[69632];
    const int bx   = blockIdx.x;
    const int tid  = threadIdx.x;
    const int wv   = tid >> 6;        // 0..7
    const int lane = tid & 63;
    const int lr   = lane & 15;
    const int lk   = lane >> 4;

    if (bx < CONV_KEY_BLK) {
        // ---------------- key role ----------------
        ushort (*h1s)[536] = (ushort(*)[536])smem;
        float (*k2part)[8] = (float(*)[8])(smem + 32 * 536 * 2);
        const int m0 = bx * 32;

        // stage 1: K=768, N=512; wave cols [wv*64,+64), rows 2x16; SW-pipelined
        {
            const ushort* arow0;
            const ushort* arow1;
            {
                const int m = m0 + lr;
                arow0 = kp + (size_t)(m >> 9) * (514 * 256) + (size_t)(m & 511) * 256 + lk * 8;
                const int m1 = m0 + 16 + lr;
                arow1 = kp + (size_t)(m1 >> 9) * (514 * 256) + (size_t)(m1 & 511) * 256 + lk * 8;
            }
            const ushort* wtb = w1t + (size_t)(wv * 64 + lr) * 768 + lk * 8;
            f32x4 acc[2][4];
            #pragma unroll
            for (int mf = 0; mf < 2; ++mf)
                #pragma unroll
                for (int f = 0; f < 4; ++f) acc[mf][f] = (f32x4){0.f, 0.f, 0.f, 0.f};

            short8v a0 = *(const short8v*)(arow0);
            short8v a1 = *(const short8v*)(arow1);
            short8v b0 = *(const short8v*)(wtb);
            short8v b1 = *(const short8v*)(wtb + (size_t)1 * 16 * 768);
            short8v b2 = *(const short8v*)(wtb + (size_t)2 * 16 * 768);
            short8v b3 = *(const short8v*)(wtb + (size_t)3 * 16 * 768);
            #pragma unroll
            for (int ks = 0; ks < 24; ++ks) {
                short8v na0, na1, nb0, nb1, nb2, nb3;
                if (ks < 23) {
                    const int o = (ks + 1) * 32;
                    na0 = *(const short8v*)(arow0 + o);
                    na1 = *(const short8v*)(arow1 + o);
                    nb0 = *(const short8v*)(wtb + o);
                    nb1 = *(const short8v*)(wtb + (size_t)1 * 16 * 768 + o);
                    nb2 = *(const short8v*)(wtb + (size_t)2 * 16 * 768 + o);
                    nb3 = *(const short8v*)(wtb + (size_t)3 * 16 * 768 + o);
                }
                acc[0][0] = __builtin_amdgcn_mfma_f32_16x16x32_bf16(a0, b0, acc[0][0], 0, 0, 0);
                acc[1][0] = __builtin_amdgcn_mfma_f32_16x16x32_bf16(a1, b0, acc[1][0], 0, 0, 0);
                acc[0][1] = __builtin_amdgcn_mfma_f32_16x16x32_bf16(a0, b1, acc[0][1], 0, 0, 0);
                acc[1][1] = __builtin_amdgcn_mfma_f32_16x16x32_bf16(a1, b1, acc[1][1], 0, 0, 0);
                acc[0][2] = __builtin_amdgcn_mfma_f32_16x16x32_bf16(a0, b2, acc[0][2], 0, 0, 0);
                acc[1][2] = __builtin_amdgcn_mfma_f32_16x16x32_bf16(a1, b2, acc[1][2], 0, 0, 0);
                acc[0][3] = __builtin_amdgcn_mfma_f32_16x16x32_bf16(a0, b3, acc[0][3], 0, 0, 0);
                acc[1][3] = __builtin_amdgcn_mfma_f32_16x16x32_bf16(a1, b3, acc[1][3], 0, 0, 0);
                if (ks < 23) {
                    a0 = na0; a1 = na1; b0 = nb0; b1 = nb1; b2 = nb2; b3 = nb3;
                }
            }
            #pragma unroll
            for (int f = 0; f < 4; ++f) {
                const int col = wv * 64 + f * 16 + lr;
                const float bv = kb1[col];
                #pragma unroll
                for (int mf = 0; mf < 2; ++mf)
                    #pragma unroll
                    for (int r = 0; r < 4; ++r)
                        h1s[mf * 16 + lk * 4 + r][col] = f2bf(fmaxf(acc[mf][f][r] + bv, 0.f));
            }
        }
        __syncthreads();

        // stage 2: K=512 (LDS), N=256; wave cols [wv*32,+32); SW-pipelined B; k2 folded
        {
            f32x4 acc[2][2];
            #pragma unroll
            for (int mf = 0; mf < 2; ++mf)
                #pragma unroll
                for (int f = 0; f < 2; ++f) acc[mf][f] = (f32x4){0.f, 0.f, 0.f, 0.f};
            const ushort* w2b = w2t + (size_t)(wv * 32 + lr) * 512 + lk * 8;
            short8v b0 = *(const short8v*)(w2b);
            short8v b1 = *(const short8v*)(w2b + (size_t)16 * 512);
            #pragma unroll
            for (int ks = 0; ks < 16; ++ks) {
                short8v nb0, nb1;
                if (ks < 15) {
                    const int o = (ks + 1) * 32;
                    nb0 = *(const short8v*)(w2b + o);
                    nb1 = *(const short8v*)(w2b + (size_t)16 * 512 + o);
                }
                const short8v a0 = *(const short8v*)&h1s[lr][lk * 8 + ks * 32];
                const short8v a1 = *(const short8v*)&h1s[16 + lr][lk * 8 + ks * 32];
                acc[0][0] = __builtin_amdgcn_mfma_f32_16x16x32_bf16(a0, b0, acc[0][0], 0, 0, 0);
                acc[1][0] = __builtin_amdgcn_mfma_f32_16x16x32_bf16(a1, b0, acc[1][0], 0, 0, 0);
                acc[0][1] = __builtin_amdgcn_mfma_f32_16x16x32_bf16(a0, b1, acc[0][1], 0, 0, 0);
                acc[1][1] = __builtin_amdgcn_mfma_f32_16x16x32_bf16(a1, b1, acc[1][1], 0, 0, 0);
                if (ks < 15) { b0 = nb0; b1 = nb1; }
            }
            float ss[2][4];
            #pragma unroll
            for (int mf = 0; mf < 2; ++mf)
                #pragma unroll
                for (int r = 0; r < 4; ++r) ss[mf][r] = 0.f;
            #pragma unroll
            for (int f = 0; f < 2; ++f) {
                const int col = wv * 32 + f * 16 + lr;
                const float bv = kb2[col];
                #pragma unroll
                for (int mf = 0; mf < 2; ++mf)
                    #pragma unroll
                    for (int r = 0; r < 4; ++r) {
                        const float o = acc[mf][f][r] + bv;
                        ke[(size_t)(m0 + mf * 16 + lk * 4 + r) * 256 + col] = f2bf(o);
                        ss[mf][r] += o * o;
                    }
            }
            #pragma unroll
            for (int mf = 0; mf < 2; ++mf)
                #pragma unroll
                for (int r = 0; r < 4; ++r) {
                    #pragma unroll
                    for (int off = 1; off < 16; off <<= 1)
                        ss[mf][r] += __shfl_xor(ss[mf][r], off);
                }
            if (lr == 0) {
                #pragma unroll
                for (int mf = 0; mf < 2; ++mf)
                    #pragma unroll
                    for (int r = 0; r < 4; ++r)
                        k2part[mf * 16 + lk * 4 + r][wv] = ss[mf][r];
            }
        }
        __syncthreads();
        if (tid < 32) {
            float s = 0.f;
            #pragma unroll
            for (int w = 0; w < 8; ++w) s += k2part[tid][w];
            k2[m0 + tid] = -TEMP * s;
        }
        return;
    }
    // ---------------- query role ----------------
    {
        ushort (*s1)[168] = (ushort(*)[168])smem;
        ushort (*s2)[104] = (ushort(*)[104])(smem + 128 * 168 * 2);
        const int m0 = (bx - CONV_KEY_BLK) * 128;
        const int cg = wv >> 2;           // col half
        const int rb = (wv & 3) * 32;     // row base (2 row-frags)

        #pragma unroll
        for (int i = 0; i < 4; ++i) {
            const int e = tid * 4 + i;
            s2[e >> 4][80 + (e & 15)] = 0;
        }

        // stage q1: K=256pad, N=160; cg covers 5 col-frags; rows 2x16; SW-pipelined
        {
            const ushort* arow0;
            const ushort* arow1;
            {
                const int m = m0 + rb + lr;
                arow0 = qp + (size_t)(m >> 11) * (2050 * 80) + (size_t)(m & 2047) * 80 + lk * 8;
                const int m1 = m0 + rb + 16 + lr;
                arow1 = qp + (size_t)(m1 >> 11) * (2050 * 80) + (size_t)(m1 & 2047) * 80 + lk * 8;
            }
            const ushort* w3b = w3t + (size_t)(cg * 5 * 16 + lr) * 256 + lk * 8;
            f32x4 acc[2][5];
            #pragma unroll
            for (int mf = 0; mf < 2; ++mf)
                #pragma unroll
                for (int f = 0; f < 5; ++f) acc[mf][f] = (f32x4){0.f, 0.f, 0.f, 0.f};

            short8v a0 = *(const short8v*)(arow0);
            short8v a1 = *(const short8v*)(arow1);
            short8v bq[5];
            #pragma unroll
            for (int f = 0; f < 5; ++f)
                bq[f] = *(const short8v*)(w3b + (size_t)f * 16 * 256);
            #pragma unroll
            for (int ks = 0; ks < 8; ++ks) {
                short8v na0, na1, nb[5];
                if (ks < 7) {
                    const int o = (ks + 1) * 32;
                    na0 = *(const short8v*)(arow0 + o);
                    na1 = *(const short8v*)(arow1 + o);
                    #pragma unroll
                    for (int f = 0; f < 5; ++f)
                        nb[f] = *(const short8v*)(w3b + (size_t)f * 16 * 256 + o);
                }
                #pragma unroll
                for (int f = 0; f < 5; ++f) {
                    acc[0][f] = __builtin_amdgcn_mfma_f32_16x16x32_bf16(a0, bq[f], acc[0][f], 0, 0, 0);
                    acc[1][f] = __builtin_amdgcn_mfma_f32_16x16x32_bf16(a1, bq[f], acc[1][f], 0, 0, 0);
                }
                if (ks < 7) {
                    a0 = na0; a1 = na1;
                    #pragma unroll
                    for (int f = 0; f < 5; ++f) bq[f] = nb[f];
                }
            }
            #pragma unroll
            for (int f = 0; f < 5; ++f) {
                const int col = (cg * 5 + f) * 16 + lr;
                const float bv = qb1[col];
                #pragma unroll
                for (int mf = 0; mf < 2; ++mf)
                    #pragma unroll
                    for (int r = 0; r < 4; ++r)
                        s1[rb + mf * 16 + lk * 4 + r][col] = f2bf(fmaxf(acc[mf][f][r] + bv, 0.f));
            }
        }
        __syncthreads();

        // stage q2: K=160, N=80 (5 frags: cg0 -> 3, cg1 -> 2); rows 2x16
        {
            const int nf = cg ? 2 : 3;
            const int f0 = cg ? 3 : 0;
            f32x4 acc[2][3];
            #pragma unroll
            for (int mf = 0; mf < 2; ++mf)
                #pragma unroll
                for (int f = 0; f < 3; ++f) acc[mf][f] = (f32x4){0.f, 0.f, 0.f, 0.f};
            #pragma unroll
            for (int ks = 0; ks < 5; ++ks) {
                const short8v a0 = *(const short8v*)&s1[rb + lr][lk * 8 + ks * 32];
                const short8v a1 = *(const short8v*)&s1[rb + 16 + lr][lk * 8 + ks * 32];
                #pragma unroll
                for (int f = 0; f < 3; ++f) {
                    if (f < nf) {
                        const short8v b = *(const short8v*)(w4t + (size_t)((f0 + f) * 16 + lr) * 160
                                                                + lk * 8 + ks * 32);
                        acc[0][f] = __builtin_amdgcn_mfma_f32_16x16x32_bf16(a0, b, acc[0][f], 0, 0, 0);
                        acc[1][f] = __builtin_amdgcn_mfma_f32_16x16x32_bf16(a1, b, acc[1][f], 0, 0, 0);
                    }
                }
            }
            #pragma unroll
            for (int f = 0; f < 3; ++f) {
                if (f < nf) {
                    const int col = (f0 + f) * 16 + lr;
                    const float bv = qb2[col];
                    #pragma unroll
                    for (int mf = 0; mf < 2; ++mf)
                        #pragma unroll
                        for (int r = 0; r < 4; ++r)
                            s2[rb + mf * 16 + lk * 4 + r][col] = f2bf(fmaxf(acc[mf][f][r] + bv, 0.f));
                }
            }
        }
        __syncthreads();

        // stage q3: K=96pad, N=256 (16 frags: 8 per cg); rows 2x16
        {
            f32x4 acc[2][8];
            #pragma unroll
            for (int mf = 0; mf < 2; ++mf)
                #pragma unroll
                for (int f = 0; f < 8; ++f) acc[mf][f] = (f32x4){0.f, 0.f, 0.f, 0.f};
            #pragma unroll
            for (int ks = 0; ks < 3; ++ks) {
                const short8v a0 = *(const short8v*)&s2[rb + lr][lk * 8 + ks * 32];
                const short8v a1 = *(const short8v*)&s2[rb + 16 + lr][lk * 8 + ks * 32];
                #pragma unroll
                for (int f = 0; f < 8; ++f) {
                    const short8v b = *(const short8v*)(w5t + (size_t)((cg * 8 + f) * 16 + lr) * 96
                                                            + lk * 8 + ks * 32);
                    acc[0][f] = __builtin_amdgcn_mfma_f32_16x16x32_bf16(a0, b, acc[0][f], 0, 0, 0);
                    acc[1][f] = __builtin_amdgcn_mfma_f32_16x16x32_bf16(a1, b, acc[1][f], 0, 0, 0);
                }
            }
            #pragma unroll
            for (int f = 0; f < 8; ++f) {
                const int col = (cg * 8 + f) * 16 + lr;
                const float bv = qb3[col];
                #pragma unroll
                for (int mf = 0; mf < 2; ++mf)
                    #pragma unroll
                    for (int r = 0; r < 4; ++r)
                        qe[(size_t)(m0 + rb + mf * 16 + lk * 4 + r) * 256 + col] = f2bf(acc[mf][f][r] + bv);
            }
        }
    }
}

// ==================== KERNEL 3: fused attention — rf=4 phase 1 (64 rows/block), vectorized phase 2 ====================

__global__ __launch_bounds__(512, 4) void attn_kernel(
    const ushort* __restrict__ qe, const ushort* __restrict__ ke,
    const float* __restrict__ k2t, const ushort* __restrict__ lgp,
    const unsigned char* __restrict__ mask,
    float* __restrict__ out_attn, float* __restrict__ out_lp)
{
    __shared__ ushort S[64][520];     // bf16 logits (66.5 KB -> 2 blocks/CU)
    const int b    = blockIdx.x >> 5;           // 32 tiles per b
    const int t1_0 = (blockIdx.x & 31) << 6;    // 64 rows per tile
    const int tid  = threadIdx.x;
    const int lane = tid & 63;
    const int wv   = tid >> 6;

    // ---- phase 1: QK^T via MFMA, rf=4 (B-frag shared by 4 row-quarters), fold k2t ----
    {
        const int lr = lane & 15;
        const int lk = lane >> 4;
        const ushort* qrow[4];
        #pragma unroll
        for (int mf = 0; mf < 4; ++mf)
            qrow[mf] = qe + ((size_t)b * TT1 + t1_0 + mf * 16 + lr) * NATT + lk * 8;

        const ushort* kbase = ke + ((size_t)b * TT2 + wv * 64 + lr) * NATT + lk * 8;
        #pragma unroll
        for (int n = 0; n < 4; ++n) {
            f32x4 acc[4];
            #pragma unroll
            for (int mf = 0; mf < 4; ++mf) acc[mf] = (f32x4){0.f, 0.f, 0.f, 0.f};
            const ushort* kb = kbase + (size_t)n * 16 * NATT;
            #pragma unroll
            for (int k = 0; k < 8; ++k) {
                const short8v bfr = *(const short8v*)(kb + k * 32);
                #pragma unroll
                for (int mf = 0; mf < 4; ++mf) {
                    const short8v a = *(const short8v*)(qrow[mf] + k * 32);
                    acc[mf] = __builtin_amdgcn_mfma_f32_16x16x32_bf16(a, bfr, acc[mf], 0, 0, 0);
                }
            }
            const int col = wv * 64 + n * 16 + lr;
            const float k2v = k2t[(size_t)b * TT2 + col];
            #pragma unroll
            for (int mf = 0; mf < 4; ++mf)
                #pragma unroll
                for (int r = 0; r < 4; ++r)
                    S[mf * 16 + lk * 4 + r][col] = f2bf(fmaf(2.0f * TEMP, acc[mf][r], k2v));
        }
    }
    __syncthreads();

    // ---- phase 2: thread (rr, jj) owns cols g*128 + jj*4 + [0,4), g=0..3; 4 row-passes ----
    const int jj = tid & 31;
    unsigned int mbits = 0;
    #pragma unroll
    for (int g = 0; g < 4; ++g) {
        const uchar4 m4 = *(const uchar4*)(mask + (size_t)b * TT2 + g * 128 + jj * 4);
        if (m4.x) mbits |= 1u << (g * 4 + 0);
        if (m4.y) mbits |= 1u << (g * 4 + 1);
        if (m4.z) mbits |= 1u << (g * 4 + 2);
        if (m4.w) mbits |= 1u << (g * 4 + 3);
    }

    #pragma unroll
    for (int half = 0; half < 4; ++half) {
        const int rr = (tid >> 5) + half * 16;
        const ushort* lgr = lgp + ((size_t)b * TT1 + t1_0 + rr) * TT2;

        float sv[16], uv[16];
        #pragma unroll
        for (int g = 0; g < 4; ++g) {
            const ushort4 s4 = *(const ushort4*)&S[rr][g * 128 + jj * 4];
            const ushort4 l4 = *(const ushort4*)(lgr + g * 128 + jj * 4);
            sv[g * 4 + 0] = bf2f(s4.x); uv[g * 4 + 0] = sv[g * 4 + 0] + bf2f(l4.x);
            sv[g * 4 + 1] = bf2f(s4.y); uv[g * 4 + 1] = sv[g * 4 + 1] + bf2f(l4.y);
            sv[g * 4 + 2] = bf2f(s4.z); uv[g * 4 + 2] = sv[g * 4 + 2] + bf2f(l4.z);
            sv[g * 4 + 3] = bf2f(s4.w); uv[g * 4 + 3] = sv[g * 4 + 3] + bf2f(l4.w);
        }

        // logZ over s (full row)
        float mx1 = sv[0];
        #pragma unroll
        for (int k = 1; k < 16; ++k) mx1 = fmaxf(mx1, sv[k]);
        #pragma unroll
        for (int off = 16; off; off >>= 1) mx1 = fmaxf(mx1, __shfl_xor(mx1, off));
        float se1 = 0.f;
        #pragma unroll
        for (int k = 0; k < 16; ++k) se1 += __expf(sv[k] - mx1);
        #pragma unroll
        for (int off = 16; off; off >>= 1) se1 += __shfl_xor(se1, off);
        const float logZ = mx1 + __logf(se1);

        // masked max + inv-sumexp over u
        float mx2 = -INFINITY;
        #pragma unroll
        for (int k = 0; k < 16; ++k)
            if (!((mbits >> k) & 1)) mx2 = fmaxf(mx2, uv[k]);
        #pragma unroll
        for (int off = 16; off; off >>= 1) mx2 = fmaxf(mx2, __shfl_xor(mx2, off));
        float se2 = 0.f;
        #pragma unroll
        for (int k = 0; k < 16; ++k)
            se2 += ((mbits >> k) & 1) ? 0.f : __expf(uv[k] - mx2);
        #pragma unroll
        for (int off = 16; off; off >>= 1) se2 += __shfl_xor(se2, off);
        const float inv = 1.0f / se2;

        float* lpr = out_lp   + ((size_t)b * TT1 + t1_0 + rr) * TT2;
        float* atr = out_attn + ((size_t)b * TT1 + t1_0 + rr) * TT2;
        #pragma unroll
        for (int g = 0; g < 4; ++g) {
            f32x4 lv, av;
            #pragma unroll
            for (int i = 0; i < 4; ++i) {
                const int k = g * 4 + i;
                lv[i] = uv[k] - logZ;
                av[i] = ((mbits >> k) & 1) ? 0.f : __expf(uv[k] - mx2) * inv;
            }
            *(f32x4*)(lpr + g * 128 + jj * 4) = lv;
            *(f32x4*)(atr + g * 128 + jj * 4) = av;
        }
    }
}

// ---------------- launch ----------------

extern "C" void kernel_launch(void* const* d_in, const int* in_sizes, int n_in,
                              void* d_out, int out_size, void* d_ws, size_t ws_size,
                              hipStream_t stream) {
    const float* queries = (const float*)d_in[0];   // (B, 80, 2048)
    const float* keys    = (const float*)d_in[1];   // (B, 512, 256)
    const unsigned char* mask = (const unsigned char*)d_in[2]; // (B, 512) bool
    const float* prior   = (const float*)d_in[3];   // (B, 512, 2048)
    const float* kw1 = (const float*)d_in[4];
    const float* kb1 = (const float*)d_in[5];
    const float* kw2 = (const float*)d_in[6];
    const float* kb2 = (const float*)d_in[7];
    const float* qw1 = (const float*)d_in[8];
    const float* qb1 = (const float*)d_in[9];
    const float* qw2 = (const float*)d_in[10];
    const float* qb2 = (const float*)d_in[11];
    const float* qw3 = (const float*)d_in[12];
    const float* qb3 = (const float*)d_in[13];

    ushort* us   = (ushort*)d_ws;
    ushort* kp   = us;
    ushort* ke   = kp  + KP_SZ;
    ushort* qp   = ke  + KE_SZ;
    ushort* qe   = qp  + QP_SZ;
    ushort* w1t  = qe  + QE_SZ;
    ushort* w2t  = w1t + W1T_SZ;
    ushort* w3t  = w2t + W2T_SZ;
    ushort* w4t  = w3t + W3T_SZ;
    ushort* w5t  = w4t + W4T_SZ;
    ushort* lgp  = w5t + W5T_SZ;
    float*  k2   = (float*)(lgp + LGP_SZ);

    float* out_attn = (float*)d_out;
    float* out_lp   = out_attn + (size_t)NB * TT1 * TT2;

    prep_kernel<<<PREP_PLT_BLK + PREP_PK_BLK + PREP_WT_BLK + PREP_QT_BLK, 256, 0, stream>>>(
        keys, kp, kw1, kw2, qw1, qw2, qw3, w1t, w2t, w3t, w4t, w5t,
        queries, qp, prior, lgp);

    conv_kernel<<<CONV_KEY_BLK + CONV_QRY_BLK, 512, 0, stream>>>(
        kp, w1t, kb1, w2t, kb2, ke, k2,
        qp, w3t, qb1, w4t, qb2, w5t, qb3, qe);

    attn_kernel<<<NB * (TT1 / 64), 512, 0, stream>>>(
        qe, ke, k2, lgp, mask, out_attn, out_lp);
}

// Round 25
// 148.293 us; speedup vs baseline: 1.2555x; 1.2555x over previous
//
#include <hip/hip_runtime.h>
#include <cmath>

#define NB    16
#define TT1   2048
#define TT2   512
#define NATT  256
#define TEMP  0.0005f

// workspace element counts (ushort = bf16 unless noted)
#define KP_SZ   (NB*514*256)
#define KE_SZ   (NB*512*256)
#define QP_SZ   (NB*2050*80)
#define QE_SZ   (NB*2048*256)
#define W1T_SZ  (512*768)
#define W2T_SZ  (256*512)
#define W3T_SZ  (160*256)
#define W4T_SZ  (80*160)
#define W5T_SZ  (256*96)
#define WTOT_SZ (W1T_SZ+W2T_SZ+W3T_SZ+W4T_SZ+W5T_SZ)
#define LGP_SZ  (NB*TT1*TT2)

// prep grid (plt first: heaviest stream starts earliest)
#define PREP_PLT_BLK  ((TT1/64)*(TT2/64)*NB)   // 4096
#define PREP_PK_BLK   (KP_SZ/256)              // 8224
#define PREP_WT_BLK   (WTOT_SZ/256)            // 2354
#define PREP_QT_BLK   (NB*(TT1/64))            // 512
// conv grid
#define CONV_KEY_BLK  (NB*512/32)              // 256
#define CONV_QRY_BLK  (NB*2048/128)            // 256

typedef __attribute__((ext_vector_type(8))) short short8v;
typedef __attribute__((ext_vector_type(4))) float f32x4;

__device__ inline ushort f2bf(float f) {
    unsigned int u = __float_as_uint(f);
    u += 0x7fff + ((u >> 16) & 1);      // RNE
    return (ushort)(u >> 16);
}
__device__ inline float bf2f(ushort u) {
    return __uint_as_float(((unsigned int)u) << 16);
}

// ==================== KERNEL 1: prep (plt | pad_keys | wtrans | query transpose) ====================

__global__ __launch_bounds__(256) void prep_kernel(
    const float* __restrict__ keys, ushort* __restrict__ kp,
    const float* __restrict__ kw1, const float* __restrict__ kw2,
    const float* __restrict__ qw1, const float* __restrict__ qw2,
    const float* __restrict__ qw3,
    ushort* __restrict__ w1t, ushort* __restrict__ w2t, ushort* __restrict__ w3t,
    ushort* __restrict__ w4t, ushort* __restrict__ w5t,
    const float* __restrict__ queries, ushort* __restrict__ qp,
    const float* __restrict__ prior, ushort* __restrict__ lgp)
{
    __shared__ float T[80][65];
    const int bx  = blockIdx.x;
    const int tid = threadIdx.x;

    if (bx < PREP_PLT_BLK) {
        // ---- prior: transpose + log -> bf16 (64x64 tile), f32x4 nt reads ----
        const int l    = bx;
        const int t1_0 = (l & 31) * 64;
        const int t2_0 = ((l >> 5) & 7) * 64;
        const int b    = l >> 8;
        const int j4 = tid & 15;           // 16 f32x4 per row
        const int r0 = tid >> 4;           // 16 rows per pass
        #pragma unroll
        for (int p = 0; p < 4; ++p) {
            const f32x4 v = __builtin_nontemporal_load(
                (const f32x4*)(prior + ((size_t)b * TT2 + t2_0 + r0 + p * 16) * TT1
                                + t1_0 + j4 * 4));
            T[r0 + p * 16][j4 * 4 + 0] = v.x;
            T[r0 + p * 16][j4 * 4 + 1] = v.y;
            T[r0 + p * 16][j4 * 4 + 2] = v.z;
            T[r0 + p * 16][j4 * 4 + 3] = v.w;
        }
        __syncthreads();
        const int j  = tid & 63;
        const int i0 = (tid >> 6) * 16;
        #pragma unroll
        for (int r = 0; r < 16; ++r) {
            const int p = i0 + r;
            const float v = T[j][p];
            lgp[((size_t)b * TT1 + t1_0 + p) * TT2 + t2_0 + j] = f2bf(__logf(v + 1e-8f));
        }
        return;
    }
    if (bx < PREP_PLT_BLK + PREP_PK_BLK) {
        const int idx = (bx - PREP_PLT_BLK) * 256 + tid;
        int c = idx & 255;
        int r = (idx >> 8) % 514;
        int b = idx / (514 * 256);
        float v = 0.f;
        if (r >= 1 && r <= 512)
            v = keys[((size_t)b * 512 + (r - 1)) * 256 + c];
        kp[idx] = f2bf(v);
        return;
    }
    if (bx < PREP_PLT_BLK + PREP_PK_BLK + PREP_WT_BLK) {
        int idx = (bx - PREP_PLT_BLK - PREP_PK_BLK) * 256 + tid;
        const float* w; ushort* wt; int Kreal, Kpad, N;
        if (idx < W1T_SZ) {
            w = kw1; wt = w1t; Kreal = 768; Kpad = 768; N = 512;
        } else if ((idx -= W1T_SZ) < W2T_SZ) {
            w = kw2; wt = w2t; Kreal = 512; Kpad = 512; N = 256;
        } else if ((idx -= W2T_SZ) < W3T_SZ) {
            w = qw1; wt = w3t; Kreal = 240; Kpad = 256; N = 160;
        } else if ((idx -= W3T_SZ) < W4T_SZ) {
            w = qw2; wt = w4t; Kreal = 160; Kpad = 160; N = 80;
        } else {
            idx -= W4T_SZ;
            w = qw3; wt = w5t; Kreal = 80; Kpad = 96; N = 256;
        }
        int k = idx % Kpad;
        int n = idx / Kpad;
        wt[idx] = (k < Kreal) ? f2bf(w[(size_t)k * N + n]) : (ushort)0;
        return;
    }
    // ---- query transpose (LDS-tiled) ----
    {
        const int l  = bx - PREP_PLT_BLK - PREP_PK_BLK - PREP_WT_BLK;   // [0, 512)
        const int b  = l >> 5;
        const int t0 = (l & 31) * 64;
        const int g  = tid >> 6;
        const int j  = tid & 63;
        #pragma unroll
        for (int r = 0; r < 20; ++r) {
            const int c = g * 20 + r;
            T[c][j] = queries[((size_t)b * 80 + c) * 2048 + t0 + j];
        }
        __syncthreads();
        const int tt = tid >> 2;
        const int c0 = (tid & 3) * 20;
        ushort* qrow = qp + (size_t)b * (2050 * 80) + (size_t)(t0 + tt + 1) * 80 + c0;
        #pragma unroll
        for (int i4 = 0; i4 < 5; ++i4) {
            ushort4 st;
            st.x = f2bf(T[c0 + i4 * 4 + 0][tt]);
            st.y = f2bf(T[c0 + i4 * 4 + 1][tt]);
            st.z = f2bf(T[c0 + i4 * 4 + 2][tt]);
            st.w = f2bf(T[c0 + i4 * 4 + 3][tt]);
            *(ushort4*)(qrow + i4 * 4) = st;
        }
        if (t0 == 0 && tid < 80)
            qp[(size_t)b * (2050 * 80) + tid] = 0;
        if (t0 == 2048 - 64 && tid < 80)
            qp[(size_t)b * (2050 * 80) + (size_t)2049 * 80 + tid] = 0;
    }
}

// ==================== KERNEL 2: conv (key | query), rf=2 + software-pipelined loads ====================

__global__ __launch_bounds__(512, 4) void conv_kernel(
    const ushort* __restrict__ kp, const ushort* __restrict__ w1t,
    const float* __restrict__ kb1, const ushort* __restrict__ w2t,
    const float* __restrict__ kb2, ushort* __restrict__ ke, float* __restrict__ k2,
    const ushort* __restrict__ qp, const ushort* __restrict__ w3t,
    const float* __restrict__ qb1, const ushort* __restrict__ w4t,
    const float* __restrict__ qb2, const ushort* __restrict__ w5t,
    const float* __restrict__ qb3, ushort* __restrict__ qe)
{
    __shared__ __align__(16) unsigned char smem[69632];
    const int bx   = blockIdx.x;
    const int tid  = threadIdx.x;
    const int wv   = tid >> 6;        // 0..7
    const int lane = tid & 63;
    const int lr   = lane & 15;
    const int lk   = lane >> 4;

    if (bx < CONV_KEY_BLK) {
        // ---------------- key role ----------------
        ushort (*h1s)[536] = (ushort(*)[536])smem;
        float (*k2part)[8] = (float(*)[8])(smem + 32 * 536 * 2);
        const int m0 = bx * 32;

        // stage 1: K=768, N=512; wave cols [wv*64,+64), rows 2x16; SW-pipelined
        {
            const ushort* arow0;
            const ushort* arow1;
            {
                const int m = m0 + lr;
                arow0 = kp + (size_t)(m >> 9) * (514 * 256) + (size_t)(m & 511) * 256 + lk * 8;
                const int m1 = m0 + 16 + lr;
                arow1 = kp + (size_t)(m1 >> 9) * (514 * 256) + (size_t)(m1 & 511) * 256 + lk * 8;
            }
            const ushort* wtb = w1t + (size_t)(wv * 64 + lr) * 768 + lk * 8;
            f32x4 acc[2][4];
            #pragma unroll
            for (int mf = 0; mf < 2; ++mf)
                #pragma unroll
                for (int f = 0; f < 4; ++f) acc[mf][f] = (f32x4){0.f, 0.f, 0.f, 0.f};

            short8v a0 = *(const short8v*)(arow0);
            short8v a1 = *(const short8v*)(arow1);
            short8v b0 = *(const short8v*)(wtb);
            short8v b1 = *(const short8v*)(wtb + (size_t)1 * 16 * 768);
            short8v b2 = *(const short8v*)(wtb + (size_t)2 * 16 * 768);
            short8v b3 = *(const short8v*)(wtb + (size_t)3 * 16 * 768);
            #pragma unroll
            for (int ks = 0; ks < 24; ++ks) {
                short8v na0, na1, nb0, nb1, nb2, nb3;
                if (ks < 23) {
                    const int o = (ks + 1) * 32;
                    na0 = *(const short8v*)(arow0 + o);
                    na1 = *(const short8v*)(arow1 + o);
                    nb0 = *(const short8v*)(wtb + o);
                    nb1 = *(const short8v*)(wtb + (size_t)1 * 16 * 768 + o);
                    nb2 = *(const short8v*)(wtb + (size_t)2 * 16 * 768 + o);
                    nb3 = *(const short8v*)(wtb + (size_t)3 * 16 * 768 + o);
                }
                acc[0][0] = __builtin_amdgcn_mfma_f32_16x16x32_bf16(a0, b0, acc[0][0], 0, 0, 0);
                acc[1][0] = __builtin_amdgcn_mfma_f32_16x16x32_bf16(a1, b0, acc[1][0], 0, 0, 0);
                acc[0][1] = __builtin_amdgcn_mfma_f32_16x16x32_bf16(a0, b1, acc[0][1], 0, 0, 0);
                acc[1][1] = __builtin_amdgcn_mfma_f32_16x16x32_bf16(a1, b1, acc[1][1], 0, 0, 0);
                acc[0][2] = __builtin_amdgcn_mfma_f32_16x16x32_bf16(a0, b2, acc[0][2], 0, 0, 0);
                acc[1][2] = __builtin_amdgcn_mfma_f32_16x16x32_bf16(a1, b2, acc[1][2], 0, 0, 0);
                acc[0][3] = __builtin_amdgcn_mfma_f32_16x16x32_bf16(a0, b3, acc[0][3], 0, 0, 0);
                acc[1][3] = __builtin_amdgcn_mfma_f32_16x16x32_bf16(a1, b3, acc[1][3], 0, 0, 0);
                if (ks < 23) {
                    a0 = na0; a1 = na1; b0 = nb0; b1 = nb1; b2 = nb2; b3 = nb3;
                }
            }
            #pragma unroll
            for (int f = 0; f < 4; ++f) {
                const int col = wv * 64 + f * 16 + lr;
                const float bv = kb1[col];
                #pragma unroll
                for (int mf = 0; mf < 2; ++mf)
                    #pragma unroll
                    for (int r = 0; r < 4; ++r)
                        h1s[mf * 16 + lk * 4 + r][col] = f2bf(fmaxf(acc[mf][f][r] + bv, 0.f));
            }
        }
        __syncthreads();

        // stage 2: K=512 (LDS), N=256; wave cols [wv*32,+32); SW-pipelined B; k2 folded
        {
            f32x4 acc[2][2];
            #pragma unroll
            for (int mf = 0; mf < 2; ++mf)
                #pragma unroll
                for (int f = 0; f < 2; ++f) acc[mf][f] = (f32x4){0.f, 0.f, 0.f, 0.f};
            const ushort* w2b = w2t + (size_t)(wv * 32 + lr) * 512 + lk * 8;
            short8v b0 = *(const short8v*)(w2b);
            short8v b1 = *(const short8v*)(w2b + (size_t)16 * 512);
            #pragma unroll
            for (int ks = 0; ks < 16; ++ks) {
                short8v nb0, nb1;
                if (ks < 15) {
                    const int o = (ks + 1) * 32;
                    nb0 = *(const short8v*)(w2b + o);
                    nb1 = *(const short8v*)(w2b + (size_t)16 * 512 + o);
                }
                const short8v a0 = *(const short8v*)&h1s[lr][lk * 8 + ks * 32];
                const short8v a1 = *(const short8v*)&h1s[16 + lr][lk * 8 + ks * 32];
                acc[0][0] = __builtin_amdgcn_mfma_f32_16x16x32_bf16(a0, b0, acc[0][0], 0, 0, 0);
                acc[1][0] = __builtin_amdgcn_mfma_f32_16x16x32_bf16(a1, b0, acc[1][0], 0, 0, 0);
                acc[0][1] = __builtin_amdgcn_mfma_f32_16x16x32_bf16(a0, b1, acc[0][1], 0, 0, 0);
                acc[1][1] = __builtin_amdgcn_mfma_f32_16x16x32_bf16(a1, b1, acc[1][1], 0, 0, 0);
                if (ks < 15) { b0 = nb0; b1 = nb1; }
            }
            float ss[2][4];
            #pragma unroll
            for (int mf = 0; mf < 2; ++mf)
                #pragma unroll
                for (int r = 0; r < 4; ++r) ss[mf][r] = 0.f;
            #pragma unroll
            for (int f = 0; f < 2; ++f) {
                const int col = wv * 32 + f * 16 + lr;
                const float bv = kb2[col];
                #pragma unroll
                for (int mf = 0; mf < 2; ++mf)
                    #pragma unroll
                    for (int r = 0; r < 4; ++r) {
                        const float o = acc[mf][f][r] + bv;
                        ke[(size_t)(m0 + mf * 16 + lk * 4 + r) * 256 + col] = f2bf(o);
                        ss[mf][r] += o * o;
                    }
            }
            #pragma unroll
            for (int mf = 0; mf < 2; ++mf)
                #pragma unroll
                for (int r = 0; r < 4; ++r) {
                    #pragma unroll
                    for (int off = 1; off < 16; off <<= 1)
                        ss[mf][r] += __shfl_xor(ss[mf][r], off);
                }
            if (lr == 0) {
                #pragma unroll
                for (int mf = 0; mf < 2; ++mf)
                    #pragma unroll
                    for (int r = 0; r < 4; ++r)
                        k2part[mf * 16 + lk * 4 + r][wv] = ss[mf][r];
            }
        }
        __syncthreads();
        if (tid < 32) {
            float s = 0.f;
            #pragma unroll
            for (int w = 0; w < 8; ++w) s += k2part[tid][w];
            k2[m0 + tid] = -TEMP * s;
        }
        return;
    }
    // ---------------- query role ----------------
    {
        ushort (*s1)[168] = (ushort(*)[168])smem;
        ushort (*s2)[104] = (ushort(*)[104])(smem + 128 * 168 * 2);
        const int m0 = (bx - CONV_KEY_BLK) * 128;
        const int cg = wv >> 2;           // col half
        const int rb = (wv & 3) * 32;     // row base (2 row-frags)

        #pragma unroll
        for (int i = 0; i < 4; ++i) {
            const int e = tid * 4 + i;
            s2[e >> 4][80 + (e & 15)] = 0;
        }

        // stage q1: K=256pad, N=160; cg covers 5 col-frags; rows 2x16; SW-pipelined
        {
            const ushort* arow0;
            const ushort* arow1;
            {
                const int m = m0 + rb + lr;
                arow0 = qp + (size_t)(m >> 11) * (2050 * 80) + (size_t)(m & 2047) * 80 + lk * 8;
                const int m1 = m0 + rb + 16 + lr;
                arow1 = qp + (size_t)(m1 >> 11) * (2050 * 80) + (size_t)(m1 & 2047) * 80 + lk * 8;
            }
            const ushort* w3b = w3t + (size_t)(cg * 5 * 16 + lr) * 256 + lk * 8;
            f32x4 acc[2][5];
            #pragma unroll
            for (int mf = 0; mf < 2; ++mf)
                #pragma unroll
                for (int f = 0; f < 5; ++f) acc[mf][f] = (f32x4){0.f, 0.f, 0.f, 0.f};

            short8v a0 = *(const short8v*)(arow0);
            short8v a1 = *(const short8v*)(arow1);
            short8v bq[5];
            #pragma unroll
            for (int f = 0; f < 5; ++f)
                bq[f] = *(const short8v*)(w3b + (size_t)f * 16 * 256);
            #pragma unroll
            for (int ks = 0; ks < 8; ++ks) {
                short8v na0, na1, nb[5];
                if (ks < 7) {
                    const int o = (ks + 1) * 32;
                    na0 = *(const short8v*)(arow0 + o);
                    na1 = *(const short8v*)(arow1 + o);
                    #pragma unroll
                    for (int f = 0; f < 5; ++f)
                        nb[f] = *(const short8v*)(w3b + (size_t)f * 16 * 256 + o);
                }
                #pragma unroll
                for (int f = 0; f < 5; ++f) {
                    acc[0][f] = __builtin_amdgcn_mfma_f32_16x16x32_bf16(a0, bq[f], acc[0][f], 0, 0, 0);
                    acc[1][f] = __builtin_amdgcn_mfma_f32_16x16x32_bf16(a1, bq[f], acc[1][f], 0, 0, 0);
                }
                if (ks < 7) {
                    a0 = na0; a1 = na1;
                    #pragma unroll
                    for (int f = 0; f < 5; ++f) bq[f] = nb[f];
                }
            }
            #pragma unroll
            for (int f = 0; f < 5; ++f) {
                const int col = (cg * 5 + f) * 16 + lr;
                const float bv = qb1[col];
                #pragma unroll
                for (int mf = 0; mf < 2; ++mf)
                    #pragma unroll
                    for (int r = 0; r < 4; ++r)
                        s1[rb + mf * 16 + lk * 4 + r][col] = f2bf(fmaxf(acc[mf][f][r] + bv, 0.f));
            }
        }
        __syncthreads();

        // stage q2: K=160, N=80 (5 frags: cg0 -> 3, cg1 -> 2); rows 2x16
        {
            const int nf = cg ? 2 : 3;
            const int f0 = cg ? 3 : 0;
            f32x4 acc[2][3];
            #pragma unroll
            for (int mf = 0; mf < 2; ++mf)
                #pragma unroll
                for (int f = 0; f < 3; ++f) acc[mf][f] = (f32x4){0.f, 0.f, 0.f, 0.f};
            #pragma unroll
            for (int ks = 0; ks < 5; ++ks) {
                const short8v a0 = *(const short8v*)&s1[rb + lr][lk * 8 + ks * 32];
                const short8v a1 = *(const short8v*)&s1[rb + 16 + lr][lk * 8 + ks * 32];
                #pragma unroll
                for (int f = 0; f < 3; ++f) {
                    if (f < nf) {
                        const short8v b = *(const short8v*)(w4t + (size_t)((f0 + f) * 16 + lr) * 160
                                                                + lk * 8 + ks * 32);
                        acc[0][f] = __builtin_amdgcn_mfma_f32_16x16x32_bf16(a0, b, acc[0][f], 0, 0, 0);
                        acc[1][f] = __builtin_amdgcn_mfma_f32_16x16x32_bf16(a1, b, acc[1][f], 0, 0, 0);
                    }
                }
            }
            #pragma unroll
            for (int f = 0; f < 3; ++f) {
                if (f < nf) {
                    const int col = (f0 + f) * 16 + lr;
                    const float bv = qb2[col];
                    #pragma unroll
                    for (int mf = 0; mf < 2; ++mf)
                        #pragma unroll
                        for (int r = 0; r < 4; ++r)
                            s2[rb + mf * 16 + lk * 4 + r][col] = f2bf(fmaxf(acc[mf][f][r] + bv, 0.f));
                }
            }
        }
        __syncthreads();

        // stage q3: K=96pad, N=256 (16 frags: 8 per cg); rows 2x16
        {
            f32x4 acc[2][8];
            #pragma unroll
            for (int mf = 0; mf < 2; ++mf)
                #pragma unroll
                for (int f = 0; f < 8; ++f) acc[mf][f] = (f32x4){0.f, 0.f, 0.f, 0.f};
            #pragma unroll
            for (int ks = 0; ks < 3; ++ks) {
                const short8v a0 = *(const short8v*)&s2[rb + lr][lk * 8 + ks * 32];
                const short8v a1 = *(const short8v*)&s2[rb + 16 + lr][lk * 8 + ks * 32];
                #pragma unroll
                for (int f = 0; f < 8; ++f) {
                    const short8v b = *(const short8v*)(w5t + (size_t)((cg * 8 + f) * 16 + lr) * 96
                                                            + lk * 8 + ks * 32);
                    acc[0][f] = __builtin_amdgcn_mfma_f32_16x16x32_bf16(a0, b, acc[0][f], 0, 0, 0);
                    acc[1][f] = __builtin_amdgcn_mfma_f32_16x16x32_bf16(a1, b, acc[1][f], 0, 0, 0);
                }
            }
            #pragma unroll
            for (int f = 0; f < 8; ++f) {
                const int col = (cg * 8 + f) * 16 + lr;
                const float bv = qb3[col];
                #pragma unroll
                for (int mf = 0; mf < 2; ++mf)
                    #pragma unroll
                    for (int r = 0; r < 4; ++r)
                        qe[(size_t)(m0 + rb + mf * 16 + lk * 4 + r) * 256 + col] = f2bf(acc[mf][f][r] + bv);
            }
        }
    }
}

// ==================== KERNEL 3: fused attention — rf=2 phase 1, vectorized phase 2 ====================

__global__ __launch_bounds__(512, 4) void attn_kernel(
    const ushort* __restrict__ qe, const ushort* __restrict__ ke,
    const float* __restrict__ k2t, const ushort* __restrict__ lgp,
    const unsigned char* __restrict__ mask,
    float* __restrict__ out_attn, float* __restrict__ out_lp)
{
    __shared__ ushort S[32][520];     // bf16 logits
    const int b    = blockIdx.x >> 6;           // 64 tiles per b
    const int t1_0 = (blockIdx.x & 63) << 5;    // 32 rows per tile
    const int tid  = threadIdx.x;
    const int lane = tid & 63;
    const int wv   = tid >> 6;

    // ---- phase 1: QK^T via MFMA, rf=2 (B-frag shared by 2 row-halves), fold k2t ----
    {
        const int lr = lane & 15;
        const int lk = lane >> 4;
        const ushort* qrow0 = qe + ((size_t)b * TT1 + t1_0 + lr) * NATT + lk * 8;
        const ushort* qrow1 = qe + ((size_t)b * TT1 + t1_0 + 16 + lr) * NATT + lk * 8;
        short8v a0[8], a1[8];
        #pragma unroll
        for (int k = 0; k < 8; ++k) {
            a0[k] = *(const short8v*)(qrow0 + k * 32);
            a1[k] = *(const short8v*)(qrow1 + k * 32);
        }

        const ushort* kbase = ke + ((size_t)b * TT2 + wv * 64 + lr) * NATT + lk * 8;
        #pragma unroll
        for (int n = 0; n < 4; ++n) {
            f32x4 acc0 = {0.f, 0.f, 0.f, 0.f};
            f32x4 acc1 = {0.f, 0.f, 0.f, 0.f};
            const ushort* kb = kbase + (size_t)n * 16 * NATT;
            #pragma unroll
            for (int k = 0; k < 8; ++k) {
                const short8v bfr = *(const short8v*)(kb + k * 32);
                acc0 = __builtin_amdgcn_mfma_f32_16x16x32_bf16(a0[k], bfr, acc0, 0, 0, 0);
                acc1 = __builtin_amdgcn_mfma_f32_16x16x32_bf16(a1[k], bfr, acc1, 0, 0, 0);
            }
            const int col = wv * 64 + n * 16 + lr;
            const float k2v = k2t[(size_t)b * TT2 + col];
            #pragma unroll
            for (int r = 0; r < 4; ++r) {
                S[lk * 4 + r][col]      = f2bf(fmaf(2.0f * TEMP, acc0[r], k2v));
                S[16 + lk * 4 + r][col] = f2bf(fmaf(2.0f * TEMP, acc1[r], k2v));
            }
        }
    }
    __syncthreads();

    // ---- phase 2: thread (rr, jj) owns cols g*128 + jj*4 + [0,4), g=0..3 ----
    const int jj = tid & 31;
    unsigned int mbits = 0;
    #pragma unroll
    for (int g = 0; g < 4; ++g) {
        const uchar4 m4 = *(const uchar4*)(mask + (size_t)b * TT2 + g * 128 + jj * 4);
        if (m4.x) mbits |= 1u << (g * 4 + 0);
        if (m4.y) mbits |= 1u << (g * 4 + 1);
        if (m4.z) mbits |= 1u << (g * 4 + 2);
        if (m4.w) mbits |= 1u << (g * 4 + 3);
    }

    #pragma unroll
    for (int half = 0; half < 2; ++half) {
        const int rr = (tid >> 5) + half * 16;
        const ushort* lgr = lgp + ((size_t)b * TT1 + t1_0 + rr) * TT2;

        float sv[16], uv[16];
        #pragma unroll
        for (int g = 0; g < 4; ++g) {
            const ushort4 s4 = *(const ushort4*)&S[rr][g * 128 + jj * 4];
            const ushort4 l4 = *(const ushort4*)(lgr + g * 128 + jj * 4);
            sv[g * 4 + 0] = bf2f(s4.x); uv[g * 4 + 0] = sv[g * 4 + 0] + bf2f(l4.x);
            sv[g * 4 + 1] = bf2f(s4.y); uv[g * 4 + 1] = sv[g * 4 + 1] + bf2f(l4.y);
            sv[g * 4 + 2] = bf2f(s4.z); uv[g * 4 + 2] = sv[g * 4 + 2] + bf2f(l4.z);
            sv[g * 4 + 3] = bf2f(s4.w); uv[g * 4 + 3] = sv[g * 4 + 3] + bf2f(l4.w);
        }

        // logZ over s (full row)
        float mx1 = sv[0];
        #pragma unroll
        for (int k = 1; k < 16; ++k) mx1 = fmaxf(mx1, sv[k]);
        #pragma unroll
        for (int off = 16; off; off >>= 1) mx1 = fmaxf(mx1, __shfl_xor(mx1, off));
        float se1 = 0.f;
        #pragma unroll
        for (int k = 0; k < 16; ++k) se1 += __expf(sv[k] - mx1);
        #pragma unroll
        for (int off = 16; off; off >>= 1) se1 += __shfl_xor(se1, off);
        const float logZ = mx1 + __logf(se1);

        // masked max + inv-sumexp over u
        float mx2 = -INFINITY;
        #pragma unroll
        for (int k = 0; k < 16; ++k)
            if (!((mbits >> k) & 1)) mx2 = fmaxf(mx2, uv[k]);
        #pragma unroll
        for (int off = 16; off; off >>= 1) mx2 = fmaxf(mx2, __shfl_xor(mx2, off));
        float se2 = 0.f;
        #pragma unroll
        for (int k = 0; k < 16; ++k)
            se2 += ((mbits >> k) & 1) ? 0.f : __expf(uv[k] - mx2);
        #pragma unroll
        for (int off = 16; off; off >>= 1) se2 += __shfl_xor(se2, off);
        const float inv = 1.0f / se2;

        float* lpr = out_lp   + ((size_t)b * TT1 + t1_0 + rr) * TT2;
        float* atr = out_attn + ((size_t)b * TT1 + t1_0 + rr) * TT2;
        #pragma unroll
        for (int g = 0; g < 4; ++g) {
            f32x4 lv, av;
            #pragma unroll
            for (int i = 0; i < 4; ++i) {
                const int k = g * 4 + i;
                lv[i] = uv[k] - logZ;
                av[i] = ((mbits >> k) & 1) ? 0.f : __expf(uv[k] - mx2) * inv;
            }
            *(f32x4*)(lpr + g * 128 + jj * 4) = lv;
            *(f32x4*)(atr + g * 128 + jj * 4) = av;
        }
    }
}

// ---------------- launch ----------------

extern "C" void kernel_launch(void* const* d_in, const int* in_sizes, int n_in,
                              void* d_out, int out_size, void* d_ws, size_t ws_size,
                              hipStream_t stream) {
    const float* queries = (const float*)d_in[0];   // (B, 80, 2048)
    const float* keys    = (const float*)d_in[1];   // (B, 512, 256)
    const unsigned char* mask = (const unsigned char*)d_in[2]; // (B, 512) bool
    const float* prior   = (const float*)d_in[3];   // (B, 512, 2048)
    const float* kw1 = (const float*)d_in[4];
    const float* kb1 = (const float*)d_in[5];
    const float* kw2 = (const float*)d_in[6];
    const float* kb2 = (const float*)d_in[7];
    const float* qw1 = (const float*)d_in[8];
    const float* qb1 = (const float*)d_in[9];
    const float* qw2 = (const float*)d_in[10];
    const float* qb2 = (const float*)d_in[11];
    const float* qw3 = (const float*)d_in[12];
    const float* qb3 = (const float*)d_in[13];

    ushort* us   = (ushort*)d_ws;
    ushort* kp   = us;
    ushort* ke   = kp  + KP_SZ;
    ushort* qp   = ke  + KE_SZ;
    ushort* qe   = qp  + QP_SZ;
    ushort* w1t  = qe  + QE_SZ;
    ushort* w2t  = w1t + W1T_SZ;
    ushort* w3t  = w2t + W2T_SZ;
    ushort* w4t  = w3t + W3T_SZ;
    ushort* w5t  = w4t + W4T_SZ;
    ushort* lgp  = w5t + W5T_SZ;
    float*  k2   = (float*)(lgp + LGP_SZ);

    float* out_attn = (float*)d_out;
    float* out_lp   = out_attn + (size_t)NB * TT1 * TT2;

    prep_kernel<<<PREP_PLT_BLK + PREP_PK_BLK + PREP_WT_BLK + PREP_QT_BLK, 256, 0, stream>>>(
        keys, kp, kw1, kw2, qw1, qw2, qw3, w1t, w2t, w3t, w4t, w5t,
        queries, qp, prior, lgp);

    conv_kernel<<<CONV_KEY_BLK + CONV_QRY_BLK, 512, 0, stream>>>(
        kp, w1t, kb1, w2t, kb2, ke, k2,
        qp, w3t, qb1, w4t, qb2, w5t, qb3, qe);

    attn_kernel<<<NB * (TT1 / 32), 512, 0, stream>>>(
        qe, ke, k2, lgp, mask, out_attn, out_lp);
}